// Round 1
// baseline (772.777 us; speedup 1.0000x reference)
//
#include <hip/hip_runtime.h>
#include <hip/hip_bf16.h>

// ---------------------------------------------------------------------------
// Transformer block (B=8, N=1024, D=1024, H=16, HD=64, FF=4096), fp32 in/out.
// bf16 MFMA GEMMs (fp32 accum), flash attention, fused epilogues.
// ---------------------------------------------------------------------------

typedef __attribute__((ext_vector_type(8))) short short8;
typedef __attribute__((ext_vector_type(4))) float floatx4;

__device__ __forceinline__ unsigned short f2bf(float f) {
  union { __hip_bfloat16 h; unsigned short u; } cv;
  cv.h = __float2bfloat16(f);
  return cv.u;
}

__device__ __forceinline__ void async_ld16(const void* g, void* l) {
  __builtin_amdgcn_global_load_lds(
      (const __attribute__((address_space(1))) unsigned int*)g,
      (__attribute__((address_space(3))) unsigned int*)l, 16, 0, 0);
}

// ---------------- fp32 -> bf16 weight conversion (4 elems/thread) ----------
__global__ __launch_bounds__(256) void cvt_bf16(const float* __restrict__ in,
                                                unsigned short* __restrict__ out) {
  const long i = ((long)blockIdx.x * 256 + threadIdx.x) * 4;
  const float4 v = *(const float4*)(in + i);
  ushort4 o;
  o.x = f2bf(v.x); o.y = f2bf(v.y); o.z = f2bf(v.z); o.w = f2bf(v.w);
  *(ushort4*)(out + i) = o;
}

// ---------------- LayerNorm: fp32 row -> bf16 row (one block per row) ------
__global__ __launch_bounds__(256) void ln_bf16(const float* __restrict__ x,
                                               const float* __restrict__ g,
                                               const float* __restrict__ b,
                                               unsigned short* __restrict__ out) {
  const int row = blockIdx.x;
  const int tid = threadIdx.x;
  const float4 v = ((const float4*)(x + (long)row * 1024))[tid];
  float s = v.x + v.y + v.z + v.w;
  float ss = v.x * v.x + v.y * v.y + v.z * v.z + v.w * v.w;
#pragma unroll
  for (int off = 1; off < 64; off <<= 1) {
    s += __shfl_xor(s, off);
    ss += __shfl_xor(ss, off);
  }
  __shared__ float red[8];
  const int wave = tid >> 6, lane = tid & 63;
  if (lane == 0) { red[wave] = s; red[4 + wave] = ss; }
  __syncthreads();
  if (tid == 0) {
    red[0] = red[0] + red[1] + red[2] + red[3];
    red[4] = red[4] + red[5] + red[6] + red[7];
  }
  __syncthreads();
  const float mu = red[0] * (1.f / 1024.f);
  const float var = red[4] * (1.f / 1024.f) - mu * mu;
  const float rstd = rsqrtf(var + 1e-5f);
  const int c = tid * 4;
  ushort4 o;
  o.x = f2bf((v.x - mu) * rstd * g[c + 0] + b[c + 0]);
  o.y = f2bf((v.y - mu) * rstd * g[c + 1] + b[c + 1]);
  o.z = f2bf((v.z - mu) * rstd * g[c + 2] + b[c + 2]);
  o.w = f2bf((v.w - mu) * rstd * g[c + 3] + b[c + 3]);
  ((ushort4*)(out + (long)row * 1024))[tid] = o;
}

// ---------------- GEMM: C[M,N] = A[M,K] @ B[N,K]^T, fused epilogues --------
// MODE 0: QKV scatter  (out0=Q [bh,n,hd] *0.125+qb, out1=K [bh,n,hd],
//                       out2=Vt [bh,hd,n] +vb)
// MODE 1: fp32 out = resid + acc + bias   (proj / fc2)
// MODE 2: bf16 out = gelu(acc + bias)     (fc1)
#define BM 128
#define BN 128
#define BK 32

template <int MODE>
__global__ __launch_bounds__(256) void gemm_bt(
    const unsigned short* __restrict__ A, const unsigned short* __restrict__ B,
    int M, int N, int Kd,
    const float* __restrict__ b0, const float* __restrict__ b1,
    const float* __restrict__ resid,
    void* __restrict__ out0, void* __restrict__ out1, void* __restrict__ out2) {
  __shared__ unsigned short lA[BM * BK];
  __shared__ unsigned short lB[BN * BK];
  const int tid = threadIdx.x;
  const int wave = tid >> 6, lane = tid & 63;
  const int l16 = lane & 15, quad = lane >> 4;
  const int wr = wave >> 1, wc = wave & 1;
  const long m0 = (long)blockIdx.y * BM;
  const long n0 = (long)blockIdx.x * BN;

  floatx4 acc[4][4];
#pragma unroll
  for (int i = 0; i < 4; i++)
#pragma unroll
    for (int j = 0; j < 4; j++) acc[i][j] = (floatx4){0.f, 0.f, 0.f, 0.f};

  for (int k0 = 0; k0 < Kd; k0 += BK) {
#pragma unroll
    for (int j = 0; j < 2; j++) {
      const int c = j * 256 + tid;
      const int row = c >> 2, kc = c & 3;
      async_ld16(A + (m0 + row) * Kd + k0 + kc * 8,
                 (char*)lA + (wave * 64 + j * 256) * 16);
      async_ld16(B + (n0 + row) * Kd + k0 + kc * 8,
                 (char*)lB + (wave * 64 + j * 256) * 16);
    }
    __syncthreads();
    short8 af[4], bfv[4];
#pragma unroll
    for (int mi = 0; mi < 4; mi++)
      af[mi] = *(const short8*)(lA + (wr * 64 + mi * 16 + l16) * BK + quad * 8);
#pragma unroll
    for (int ni = 0; ni < 4; ni++)
      bfv[ni] = *(const short8*)(lB + (wc * 64 + ni * 16 + l16) * BK + quad * 8);
#pragma unroll
    for (int mi = 0; mi < 4; mi++)
#pragma unroll
      for (int ni = 0; ni < 4; ni++)
        acc[mi][ni] = __builtin_amdgcn_mfma_f32_16x16x32_bf16(
            af[mi], bfv[ni], acc[mi][ni], 0, 0, 0);
    __syncthreads();
  }

#pragma unroll
  for (int mi = 0; mi < 4; mi++) {
    const long rbase = m0 + wr * 64 + mi * 16 + quad * 4;
#pragma unroll
    for (int ni = 0; ni < 4; ni++) {
      const long cg = n0 + wc * 64 + ni * 16 + l16;
#pragma unroll
      for (int reg = 0; reg < 4; reg++) {
        const long rr = rbase + reg;
        const float val = acc[mi][ni][reg];
        if (MODE == 0) {
          const int which = (int)(cg >> 10);
          const int col = (int)(cg & 1023);
          const int bidx = (int)(rr >> 10), t = (int)(rr & 1023);
          const int head = col >> 6, hd = col & 63;
          const long bh = bidx * 16 + head;
          if (which == 0) {
            ((unsigned short*)out0)[(bh * 1024 + t) * 64 + hd] =
                f2bf((val + b0[col]) * 0.125f);
          } else if (which == 1) {
            ((unsigned short*)out1)[(bh * 1024 + t) * 64 + hd] = f2bf(val);
          } else {
            ((unsigned short*)out2)[(bh * 64 + hd) * 1024 + t] =
                f2bf(val + b1[col]);
          }
        } else if (MODE == 1) {
          const long idx = rr * N + cg;
          ((float*)out0)[idx] = resid[idx] + val + b0[cg];
        } else {
          const float u = val + b0[cg];
          const float gl = 0.5f * u * (1.0f + erff(u * 0.70710678118f));
          ((unsigned short*)out0)[rr * N + cg] = f2bf(gl);
        }
      }
    }
  }
}

// ---------------- Flash attention: 1 wave per (bh, 16-row Q tile) ----------
// Q [bh,n,hd] (pre-scaled), K [bh,n,hd], Vt [bh,hd,n] -> O [b,n,h*hd]
__global__ __launch_bounds__(64) void attn(const unsigned short* __restrict__ Q,
                                           const unsigned short* __restrict__ Kc,
                                           const unsigned short* __restrict__ Vt,
                                           unsigned short* __restrict__ O) {
  __shared__ float P[16][32];
  const int lane = threadIdx.x;
  const int l16 = lane & 15, quad = lane >> 4;
  const int q0 = blockIdx.x * 16;
  const int bh = blockIdx.y;
  const unsigned short* Qb = Q + ((long)bh * 1024 + q0) * 64;
  const short8 qf0 = *(const short8*)(Qb + l16 * 64 + quad * 8);
  const short8 qf1 = *(const short8*)(Qb + l16 * 64 + 32 + quad * 8);
  floatx4 oacc[4];
#pragma unroll
  for (int t = 0; t < 4; t++) oacc[t] = (floatx4){0.f, 0.f, 0.f, 0.f};
  float mrun[4] = {-1e30f, -1e30f, -1e30f, -1e30f};
  float lrun[4] = {0.f, 0.f, 0.f, 0.f};

  for (int ks = 0; ks < 1024; ks += 32) {
    const unsigned short* Kt = Kc + ((long)bh * 1024 + ks) * 64;
    const short8 kf00 = *(const short8*)(Kt + l16 * 64 + quad * 8);
    const short8 kf01 = *(const short8*)(Kt + l16 * 64 + 32 + quad * 8);
    const short8 kf10 = *(const short8*)(Kt + (16 + l16) * 64 + quad * 8);
    const short8 kf11 = *(const short8*)(Kt + (16 + l16) * 64 + 32 + quad * 8);
    const floatx4 z = {0.f, 0.f, 0.f, 0.f};
    floatx4 s0 = __builtin_amdgcn_mfma_f32_16x16x32_bf16(qf0, kf00, z, 0, 0, 0);
    s0 = __builtin_amdgcn_mfma_f32_16x16x32_bf16(qf1, kf01, s0, 0, 0, 0);
    floatx4 s1 = __builtin_amdgcn_mfma_f32_16x16x32_bf16(qf0, kf10, z, 0, 0, 0);
    s1 = __builtin_amdgcn_mfma_f32_16x16x32_bf16(qf1, kf11, s1, 0, 0, 0);

    float alpha[4];
#pragma unroll
    for (int r = 0; r < 4; r++) {
      float mx = fmaxf(s0[r], s1[r]);
      mx = fmaxf(mx, __shfl_xor(mx, 1));
      mx = fmaxf(mx, __shfl_xor(mx, 2));
      mx = fmaxf(mx, __shfl_xor(mx, 4));
      mx = fmaxf(mx, __shfl_xor(mx, 8));
      const float mnew = fmaxf(mrun[r], mx);
      alpha[r] = __expf(mrun[r] - mnew);
      const float p0 = __expf(s0[r] - mnew);
      const float p1 = __expf(s1[r] - mnew);
      float rs = p0 + p1;
      rs += __shfl_xor(rs, 1);
      rs += __shfl_xor(rs, 2);
      rs += __shfl_xor(rs, 4);
      rs += __shfl_xor(rs, 8);
      lrun[r] = lrun[r] * alpha[r] + rs;
      mrun[r] = mnew;
      P[quad * 4 + r][l16] = p0;
      P[quad * 4 + r][16 + l16] = p1;
    }
    const floatx4 av = {alpha[0], alpha[1], alpha[2], alpha[3]};
#pragma unroll
    for (int t = 0; t < 4; t++) oacc[t] *= av;
    __syncthreads();
    // P (C-layout) -> A-operand layout via LDS: A[m=l16][k=quad*8+j]
    const floatx4* pr = (const floatx4*)&P[l16][quad * 8];
    const floatx4 pa = pr[0], pb = pr[1];
    short8 pf;
    pf[0] = (short)f2bf(pa[0]); pf[1] = (short)f2bf(pa[1]);
    pf[2] = (short)f2bf(pa[2]); pf[3] = (short)f2bf(pa[3]);
    pf[4] = (short)f2bf(pb[0]); pf[5] = (short)f2bf(pb[1]);
    pf[6] = (short)f2bf(pb[2]); pf[7] = (short)f2bf(pb[3]);
    __syncthreads();
#pragma unroll
    for (int t = 0; t < 4; t++) {
      const short8 vf = *(const short8*)(Vt + ((long)bh * 64 + t * 16 + l16) * 1024 +
                                         ks + quad * 8);
      oacc[t] = __builtin_amdgcn_mfma_f32_16x16x32_bf16(pf, vf, oacc[t], 0, 0, 0);
    }
  }
  const int b = bh >> 4, h = bh & 15;
#pragma unroll
  for (int t = 0; t < 4; t++) {
#pragma unroll
    for (int r = 0; r < 4; r++) {
      O[((long)b * 1024 + q0 + quad * 4 + r) * 1024 + h * 64 + t * 16 + l16] =
          f2bf(oacc[t][r] / lrun[r]);
    }
  }
}

// ---------------------------------------------------------------------------
extern "C" void kernel_launch(void* const* d_in, const int* in_sizes, int n_in,
                              void* d_out, int out_size, void* d_ws, size_t ws_size,
                              hipStream_t stream) {
  const float* x      = (const float*)d_in[0];
  const float* ln1_g  = (const float*)d_in[1];
  const float* ln1_b  = (const float*)d_in[2];
  const float* ln2_g  = (const float*)d_in[3];
  const float* ln2_b  = (const float*)d_in[4];
  const float* qkv_w  = (const float*)d_in[5];
  const float* q_bias = (const float*)d_in[6];
  const float* v_bias = (const float*)d_in[7];
  const float* proj_w = (const float*)d_in[8];
  const float* proj_b = (const float*)d_in[9];
  const float* fc1_w  = (const float*)d_in[10];
  const float* fc1_b  = (const float*)d_in[11];
  const float* fc2_w  = (const float*)d_in[12];
  const float* fc2_b  = (const float*)d_in[13];
  float* out = (float*)d_out;

  char* ws = (char*)d_ws;
  unsigned short* Wqkv  = (unsigned short*)(ws);              //  6 MB
  unsigned short* Wproj = (unsigned short*)(ws + 6291456);    //  2 MB
  unsigned short* Wfc1  = (unsigned short*)(ws + 8388608);    //  8 MB
  unsigned short* Wfc2  = (unsigned short*)(ws + 16777216);   //  8 MB
  float*          X1    = (float*)        (ws + 25165824);    // 32 MB fp32
  unsigned short* Hbuf  = (unsigned short*)(ws + 58720256);   // 16 MB
  unsigned short* Qbuf  = (unsigned short*)(ws + 75497472);   // 16 MB
  unsigned short* Kbuf  = (unsigned short*)(ws + 92274688);   // 16 MB
  unsigned short* Vtbuf = (unsigned short*)(ws + 109051904);  // 16 MB
  unsigned short* Obuf  = (unsigned short*)(ws + 125829120);  // 16 MB
  unsigned short* ACT   = Qbuf;  // reuse dead Q/K/Vt/O region: 64 MB

  // weights -> bf16
  cvt_bf16<<<3072 * 1024 / 1024, 256, 0, stream>>>(qkv_w, Wqkv);
  cvt_bf16<<<1024 * 1024 / 1024, 256, 0, stream>>>(proj_w, Wproj);
  cvt_bf16<<<4096 * 1024 / 1024, 256, 0, stream>>>(fc1_w, Wfc1);
  cvt_bf16<<<4096 * 1024 / 1024, 256, 0, stream>>>(fc2_w, Wfc2);

  // LN1
  ln_bf16<<<8192, 256, 0, stream>>>(x, ln1_g, ln1_b, Hbuf);
  // QKV gemm + scatter (q scaled by 1/8, v -> transposed)
  gemm_bt<0><<<dim3(24, 64), 256, 0, stream>>>(Hbuf, Wqkv, 8192, 3072, 1024,
                                               q_bias, v_bias, nullptr,
                                               Qbuf, Kbuf, Vtbuf);
  // attention
  attn<<<dim3(64, 128), 64, 0, stream>>>(Qbuf, Kbuf, Vtbuf, Obuf);
  // proj + residual -> X1 (fp32)
  gemm_bt<1><<<dim3(8, 64), 256, 0, stream>>>(Obuf, Wproj, 8192, 1024, 1024,
                                              proj_b, nullptr, x,
                                              X1, nullptr, nullptr);
  // LN2
  ln_bf16<<<8192, 256, 0, stream>>>(X1, ln2_g, ln2_b, Hbuf);
  // fc1 + gelu -> ACT (bf16)
  gemm_bt<2><<<dim3(32, 64), 256, 0, stream>>>(Hbuf, Wfc1, 8192, 4096, 1024,
                                               fc1_b, nullptr, nullptr,
                                               ACT, nullptr, nullptr);
  // fc2 + residual -> out (fp32)
  gemm_bt<1><<<dim3(8, 64), 256, 0, stream>>>(ACT, Wfc2, 8192, 1024, 4096,
                                              fc2_b, nullptr, X1,
                                              out, nullptr, nullptr);
  (void)in_sizes; (void)n_in; (void)out_size; (void)ws_size;
}